// Round 8
// baseline (415.634 us; speedup 1.0000x reference)
//
#include <hip/hip_runtime.h>
#include <cstdint>
#include <cstddef>

typedef int i32x4 __attribute__((ext_vector_type(4)));

#define BM 256
#define BN 256
#define BK 64   // bytes of K per tile; one mfma_i32_16x16x64_i8 covers the whole tile-K

__device__ __forceinline__ void load16_to_lds(const void* g, void* l) {
  __builtin_amdgcn_global_load_lds(
      (const __attribute__((address_space(1))) void*)g,
      (__attribute__((address_space(3))) void*)l,
      16, 0, 0);
}

// Fused input quantization, one WAVE per row, no barriers / no LDS (round-6, verified):
// wave-task id wid in [0, M):          per-row absmax + int8 quantize of x.
// wid in [M, M+N):                     pack one int32 weight row to int8.
__global__ __launch_bounds__(256) void quant_xw(const float* __restrict__ x,
                                                char* __restrict__ xq,
                                                float* __restrict__ sx,
                                                const int* __restrict__ w,
                                                char* __restrict__ wq,
                                                int M, int K) {
  const int wid = blockIdx.x * 4 + (threadIdx.x >> 6);
  const int l   = threadIdx.x & 63;
  if (wid < M) {
    const float4* xr = (const float4*)(x + (size_t)wid * K);
    float4 v[16];
    float amax = 0.f;
#pragma unroll
    for (int j = 0; j < 16; ++j) {
      v[j] = xr[j * 64 + l];
      amax = fmaxf(amax, fmaxf(fmaxf(fabsf(v[j].x), fabsf(v[j].y)),
                               fmaxf(fabsf(v[j].z), fabsf(v[j].w))));
    }
#pragma unroll
    for (int off = 32; off; off >>= 1)
      amax = fmaxf(amax, __shfl_xor(amax, off));
    amax = fmaxf(amax, 1e-20f);

    const float s = 127.0f / amax;
    int* outw = (int*)(xq + (size_t)wid * K);
#pragma unroll
    for (int j = 0; j < 16; ++j) {
      int q0 = __float2int_rn(v[j].x * s);
      int q1 = __float2int_rn(v[j].y * s);
      int q2 = __float2int_rn(v[j].z * s);
      int q3 = __float2int_rn(v[j].w * s);
      outw[j * 64 + l] = (q0 & 0xff) | ((q1 & 0xff) << 8) |
                         ((q2 & 0xff) << 16) | ((q3 & 0xff) << 24);
    }
    if (l == 0) sx[wid] = amax * (1.0f / 127.0f);
  } else {
    const int r = wid - M;
    const int4* wr = (const int4*)(w + (size_t)r * K);
    int* outw = (int*)(wq + (size_t)r * K);
#pragma unroll
    for (int j = 0; j < 16; ++j) {
      int4 a = wr[j * 64 + l];
      outw[j * 64 + l] = (a.x & 0xff) | ((a.y & 0xff) << 8) |
                         ((a.z & 0xff) << 16) | ((a.w & 0xff) << 24);
    }
  }
}

// C[m][n] = sum_k A[m][k]*Bw[n][k] (int8 -> int32); out = C*sx[m]*sw[n] + bias[n].
// 256x256 tile, 1024 thr (16 waves: 4M x 4N -> 64x64 per wave), BK=64B,
// mfma_i32_16x16x64_i8. ROUND-5 PHASE BODIES (verified best), buffers 3 -> 2:
// LDS 96 -> 64 KiB => 2 blocks/CU resident (32 waves/CU). Cross-block wave overlap
// absorbs the boundary drain (m97/m114 mechanism); prefetch depth 1:
//   P0(t): ds_read a0,a1,b0..b3; stage A(t+1)->buf^1; bar; lgkm0; 8 MFMA; bar
//   P1(t): ds_read a2,a3;        stage B(t+1)->buf^1; bar; lgkm0; 8 MFMA;
//          vmcnt(0) [t+1's pair, issued a full tile earlier]; bar
// WAR: DMA into buf^1 at tile t start is safe — tile t-1's ds_reads of buf^1 were
// lgkm-drained before its P1 cluster, which precedes the boundary barrier.
// LDS swizzle (verified conflict-free): 16B chunk (row r, chunk c) at byte
// r*64 + ((c^((r>>1)&3))<<4); staged via pre-swizzled global source, linear DMA dst.
__global__ __launch_bounds__(1024) void gemm_i8_bt(const char* __restrict__ A,
                                                   const char* __restrict__ Bw,
                                                   const float* __restrict__ sx,
                                                   const float* __restrict__ sw,
                                                   const float* __restrict__ bias,
                                                   float* __restrict__ out,
                                                   int M, int N, int K) {
  __shared__ __align__(16) char As[2][BM * BK];   // 2 x 16 KiB
  __shared__ __align__(16) char Bs[2][BN * BK];   // 2 x 16 KiB  (64 KiB total)

  const int tid  = threadIdx.x;
  const int wave = tid >> 6;
  const int lane = tid & 63;
  const int wm   = wave >> 2;      // 0..3 -> 64-row block
  const int wn   = wave & 3;       // 0..3 -> 64-col block

  // XCD-aware bijective block swizzle (nwg = 512, divisible by 8)
  const int gx   = N / BN;                              // 16
  const int nwg  = gx * (M / BM);                       // 512
  const int orig = blockIdx.y * gx + blockIdx.x;
  const int wg   = (orig & 7) * (nwg >> 3) + (orig >> 3);
  const int bn   = wg % gx;
  const int bm   = wg / gx;

  i32x4 acc[4][4] = {};

  // Staging: thread stages 16B chunk q=tid of each tile (1024 x 16B = 16 KiB).
  // LDS chunk position p=q&3 of row q>>2 holds global chunk p ^ ((row>>1)&3).
  const int rowT = tid >> 2;
  const int jg   = ((tid & 3) ^ ((tid >> 3) & 3)) << 4;
  const char* Ag = A  + (size_t)(bm * BM + rowT) * K + jg;
  const char* Bg = Bw + (size_t)(bn * BN + rowT) * K + jg;

  const int ldsO = wave << 10;    // chunk q=tid -> byte tid*16 (wave-uniform base)

  // Fragment read offsets: row R, k-chunk j=lane>>4 at byte R*64 + ((j^((R>>1)&3))<<4).
  // ((R>>1)&3) == ((fr>>1)&3): wm*64 and m*16 are 0 mod 16.
  const int fr  = lane & 15;
  const int swz = (((lane >> 4) ^ ((fr >> 1) & 3)) << 4);
  int offA[4], offB[4];
#pragma unroll
  for (int m = 0; m < 4; ++m) offA[m] = (wm * 64 + m * 16 + fr) * 64 + swz;
#pragma unroll
  for (int n = 0; n < 4; ++n) offB[n] = (wn * 64 + n * 16 + fr) * 64 + swz;

  const int NT = K / BK;    // 64

  // Prologue: stage tile 0 into buffer 0; drain; barrier.
  load16_to_lds(Ag, &As[0][ldsO]);
  load16_to_lds(Bg, &Bs[0][ldsO]);
  asm volatile("s_waitcnt vmcnt(0)" ::: "memory");
  __builtin_amdgcn_s_barrier();

  int buf = 0;                              // tile t lives in buffer t & 1
  for (int t = 0; t < NT; ++t) {
    const int  nb = buf ^ 1;
    const size_t ko = (size_t)(t + 1) * BK;
    const bool pf = (t + 1) < NT;

    // ---------------- P0: a0,a1 x b0..b3 ----------------
    i32x4 a0 = *(const i32x4*)&As[buf][offA[0]];
    i32x4 a1 = *(const i32x4*)&As[buf][offA[1]];
    i32x4 b0 = *(const i32x4*)&Bs[buf][offB[0]];
    i32x4 b1 = *(const i32x4*)&Bs[buf][offB[1]];
    i32x4 b2 = *(const i32x4*)&Bs[buf][offB[2]];
    i32x4 b3 = *(const i32x4*)&Bs[buf][offB[3]];
    if (pf) load16_to_lds(Ag + ko, &As[nb][ldsO]);
    __builtin_amdgcn_s_barrier();
    asm volatile("s_waitcnt lgkmcnt(0)" ::: "memory");
    __builtin_amdgcn_sched_barrier(0);
    __builtin_amdgcn_s_setprio(1);
    acc[0][0] = __builtin_amdgcn_mfma_i32_16x16x64_i8(a0, b0, acc[0][0], 0, 0, 0);
    acc[0][1] = __builtin_amdgcn_mfma_i32_16x16x64_i8(a0, b1, acc[0][1], 0, 0, 0);
    acc[0][2] = __builtin_amdgcn_mfma_i32_16x16x64_i8(a0, b2, acc[0][2], 0, 0, 0);
    acc[0][3] = __builtin_amdgcn_mfma_i32_16x16x64_i8(a0, b3, acc[0][3], 0, 0, 0);
    acc[1][0] = __builtin_amdgcn_mfma_i32_16x16x64_i8(a1, b0, acc[1][0], 0, 0, 0);
    acc[1][1] = __builtin_amdgcn_mfma_i32_16x16x64_i8(a1, b1, acc[1][1], 0, 0, 0);
    acc[1][2] = __builtin_amdgcn_mfma_i32_16x16x64_i8(a1, b2, acc[1][2], 0, 0, 0);
    acc[1][3] = __builtin_amdgcn_mfma_i32_16x16x64_i8(a1, b3, acc[1][3], 0, 0, 0);
    __builtin_amdgcn_s_setprio(0);
    __builtin_amdgcn_s_barrier();

    // ---------------- P1: a2,a3 x b0..b3 ----------------
    i32x4 a2 = *(const i32x4*)&As[buf][offA[2]];
    i32x4 a3 = *(const i32x4*)&As[buf][offA[3]];
    if (pf) load16_to_lds(Bg + ko, &Bs[nb][ldsO]);
    __builtin_amdgcn_s_barrier();
    asm volatile("s_waitcnt lgkmcnt(0)" ::: "memory");
    __builtin_amdgcn_sched_barrier(0);
    __builtin_amdgcn_s_setprio(1);
    acc[2][0] = __builtin_amdgcn_mfma_i32_16x16x64_i8(a2, b0, acc[2][0], 0, 0, 0);
    acc[2][1] = __builtin_amdgcn_mfma_i32_16x16x64_i8(a2, b1, acc[2][1], 0, 0, 0);
    acc[2][2] = __builtin_amdgcn_mfma_i32_16x16x64_i8(a2, b2, acc[2][2], 0, 0, 0);
    acc[2][3] = __builtin_amdgcn_mfma_i32_16x16x64_i8(a2, b3, acc[2][3], 0, 0, 0);
    acc[3][0] = __builtin_amdgcn_mfma_i32_16x16x64_i8(a3, b0, acc[3][0], 0, 0, 0);
    acc[3][1] = __builtin_amdgcn_mfma_i32_16x16x64_i8(a3, b1, acc[3][1], 0, 0, 0);
    acc[3][2] = __builtin_amdgcn_mfma_i32_16x16x64_i8(a3, b2, acc[3][2], 0, 0, 0);
    acc[3][3] = __builtin_amdgcn_mfma_i32_16x16x64_i8(a3, b3, acc[3][3], 0, 0, 0);
    __builtin_amdgcn_s_setprio(0);

    // Tile boundary: drain tile t+1's pair (issued a full tile earlier).
    if (pf) { asm volatile("s_waitcnt vmcnt(0)" ::: "memory"); }
    __builtin_amdgcn_s_barrier();

    buf = nb;
  }

  // Epilogue. C/D layout (dtype-independent): col = lane&15, row = (lane>>4)*4 + reg.
  const int colc = lane & 15;
  const int rq   = (lane >> 4) << 2;
  float sxv[4][4];
#pragma unroll
  for (int m = 0; m < 4; ++m) {
    const int row0 = bm * BM + wm * 64 + m * 16 + rq;
#pragma unroll
    for (int r = 0; r < 4; ++r) sxv[m][r] = sx[row0 + r];
  }
#pragma unroll
  for (int n = 0; n < 4; ++n) {
    const int col = bn * BN + wn * 64 + n * 16 + colc;
    const float sc = sw[col];
    const float bi = bias[col];
#pragma unroll
    for (int m = 0; m < 4; ++m) {
      const int row0 = bm * BM + wm * 64 + m * 16 + rq;
#pragma unroll
      for (int r = 0; r < 4; ++r)
        out[(size_t)(row0 + r) * N + col] = (float)acc[m][n][r] * (sxv[m][r] * sc) + bi;
    }
  }
}

extern "C" void kernel_launch(void* const* d_in, const int* in_sizes, int n_in,
                              void* d_out, int out_size, void* d_ws, size_t ws_size,
                              hipStream_t stream) {
  const float* x     = (const float*)d_in[0];
  const int*   w     = (const int*)d_in[1];
  const float* scale = (const float*)d_in[2];
  const float* bias  = (const float*)d_in[3];
  float*       out   = (float*)d_out;

  const int N = in_sizes[3];          // D_OUT = 4096
  const int K = in_sizes[1] / N;      // D_IN  = 4096
  const int M = in_sizes[0] / K;      // B*S   = 8192

  char*  xq = (char*)d_ws;                       // M*K i8  = 32 MiB
  char*  wq = xq + (size_t)M * K;                // N*K i8  = 16 MiB
  float* sx = (float*)(wq + (size_t)N * K);      // M floats

  // Wave-tasks: M x-rows + N w-rows; 4 waves per 256-thr block.
  const unsigned nwaves = (unsigned)(M + N);
  quant_xw<<<dim3(nwaves / 4), dim3(256), 0, stream>>>(x, xq, sx, w, wq, M, K);

  gemm_i8_bt<<<dim3(N / BN, M / BM), dim3(1024), 0, stream>>>(xq, wq, sx, scale, bias, out, M, N, K);
}